// Round 2
// baseline (676.768 us; speedup 1.0000x reference)
//
#include <hip/hip_runtime.h>
#include <hip/hip_bf16.h>
#include <math.h>

typedef __bf16 bf16_t;
typedef __bf16 bf16x8 __attribute__((ext_vector_type(8)));
typedef float  f32x4  __attribute__((ext_vector_type(4)));

#define QKV_SCALE 0.17677669529663687f   // 32^-0.5

// workspace offsets (bytes)
#define WS_QKVWT   0u          // [384][128] bf16 (col-major-of-original = wT[n][k])
#define WS_PROJWT  98304u      // [128][128] bf16
#define WS_BM      131072u     // [64][4][49][49] f32  (mask + mlp bias)

// ---------------------------------------------------------------- prep ----
__global__ __launch_bounds__(256) void prep_kernel(
    const float* __restrict__ mask,
    const float* __restrict__ qkv_w,
    const float* __restrict__ mlp_w1, const float* __restrict__ mlp_b1,
    const float* __restrict__ mlp_w2, const float* __restrict__ mlp_b2,
    const float* __restrict__ proj_w,
    bf16_t* __restrict__ qkv_wT, bf16_t* __restrict__ proj_wT,
    float* __restrict__ bm)
{
    const int blk = blockIdx.x;
    const int tid = threadIdx.x;
    if (blk < 10) {
        const int nm = blk * 256 + tid;
        if (nm < 49 * 49) {
            const int n = nm / 49, m = nm % 49;
            const float dy = (float)(n / 7 - m / 7) * (1.0f / 6.0f);
            const float dx = (float)(n % 7 - m % 7) * (1.0f / 6.0f);
            float b0 = mlp_b2[0], b1 = mlp_b2[1], b2 = mlp_b2[2], b3 = mlp_b2[3];
            for (int j = 0; j < 64; ++j) {
                const float pre = dy * mlp_w1[j] + dx * mlp_w1[64 + j] + mlp_b1[j];
                const float g = 0.5f * pre * (1.0f + erff(pre * 0.70710678118654752f));
                b0 += g * mlp_w2[j * 4 + 0];
                b1 += g * mlp_w2[j * 4 + 1];
                b2 += g * mlp_w2[j * 4 + 2];
                b3 += g * mlp_w2[j * 4 + 3];
            }
            for (int wi = 0; wi < 64; ++wi) {
                const float mv = mask[wi * 2401 + nm];
                bm[(size_t)((wi * 4 + 0) * 2401) + nm] = mv + b0;
                bm[(size_t)((wi * 4 + 1) * 2401) + nm] = mv + b1;
                bm[(size_t)((wi * 4 + 2) * 2401) + nm] = mv + b2;
                bm[(size_t)((wi * 4 + 3) * 2401) + nm] = mv + b3;
            }
        }
    } else if (blk < 202) {
        const int idx = (blk - 10) * 256 + tid;        // 0..49151
        const int n = idx >> 7, k = idx & 127;
        qkv_wT[idx] = (bf16_t)qkv_w[k * 384 + n];
    } else {
        const int idx = (blk - 202) * 256 + tid;       // 0..16383
        const int n = idx >> 7, k = idx & 127;
        proj_wT[idx] = (bf16_t)proj_w[k * 128 + n];
    }
}

// ---------------------------------------------------------------- main ----
// LDS map (65536 B total):
//   [0, 16384)                : xb  [64 rows][128] bf16 (swz) -> later os [64][128]
//   [16384 + w*12288, +8192)  : per-wave qk [64 rows][64] bf16 (Q cols 0-31, K cols 32-63) -> later P [64][64]
//   [  ... + 8192, +4096)     : per-wave vt [32 dims][64 keys] bf16
// swizzle: byte ^= (row & 7) << 4   (applied on BOTH write and read — rule #21)
__global__ __launch_bounds__(256, 2) void swin_main_kernel(
    const float* __restrict__ x,
    const float* __restrict__ qkv_b,
    const float* __restrict__ proj_b,
    const bf16_t* __restrict__ qkv_wT,
    const bf16_t* __restrict__ proj_wT,
    const float* __restrict__ bm,
    float* __restrict__ out)
{
    __shared__ __align__(16) unsigned char smem[65536];

    const int b    = blockIdx.x;
    const int tid  = threadIdx.x;
    const int w    = tid >> 6;          // wave = head
    const int lane = tid & 63;
    const int c16  = lane & 15;
    const int q4   = lane >> 4;
    const int WB   = 16384 + w * 12288; // qk / P base
    const int VB   = WB + 8192;         // vt base

    // ---- stage 0: X -> bf16 LDS (swizzled); rows 49..63 zero-padded ----
    const float* xg = x + (size_t)b * (49 * 128);
    for (int c = tid; c < 1024; c += 256) {         // 64 rows * 16 chunks(8 elems)
        const int row = c >> 4;
        const int k8  = (c & 15) << 3;
        const int off = ((row << 8) + (k8 << 1)) ^ ((row & 7) << 4);
        if (row < 49) {
            const float* p = xg + row * 128 + k8;
            float4 a0 = *(const float4*)p;
            float4 a1 = *(const float4*)(p + 4);
            bf16x8 v;
            v[0] = (bf16_t)a0.x; v[1] = (bf16_t)a0.y; v[2] = (bf16_t)a0.z; v[3] = (bf16_t)a0.w;
            v[4] = (bf16_t)a1.x; v[5] = (bf16_t)a1.y; v[6] = (bf16_t)a1.z; v[7] = (bf16_t)a1.w;
            *(bf16x8*)&smem[off] = v;
        } else {
            int4 z = {0, 0, 0, 0};
            *(int4*)&smem[off] = z;
        }
    }
    __syncthreads();

    // ---- GEMM1: QKV = Xb @ Wqkv ; wave w computes its head's Q,K,V cols ----
    const int ct0 = 2 * w, ct1 = 2 * w + 1;
    const int ct[6] = {ct0, ct1, 8 + ct0, 8 + ct1, 16 + ct0, 16 + ct1};
    f32x4 zf = {0.f, 0.f, 0.f, 0.f};
    f32x4 acc[4][6];
#pragma unroll
    for (int mt = 0; mt < 4; ++mt)
#pragma unroll
        for (int j = 0; j < 6; ++j) acc[mt][j] = zf;

#pragma unroll
    for (int s = 0; s < 4; ++s) {
        bf16x8 afr[4];
#pragma unroll
        for (int mt = 0; mt < 4; ++mt) {
            const int row = mt * 16 + c16;
            const int off = ((row << 8) + ((s * 32 + q4 * 8) << 1)) ^ ((row & 7) << 4);
            afr[mt] = *(const bf16x8*)&smem[off];
        }
#pragma unroll
        for (int j = 0; j < 6; ++j) {
            const bf16x8 bfr = *(const bf16x8*)(qkv_wT + (ct[j] * 16 + c16) * 128 + s * 32 + q4 * 8);
#pragma unroll
            for (int mt = 0; mt < 4; ++mt)
                acc[mt][j] = __builtin_amdgcn_mfma_f32_16x16x32_bf16(afr[mt], bfr, acc[mt][j], 0, 0, 0);
        }
    }

    // ---- GEMM1 epilogue: +bias, scale Q, scatter to qk / vt (bf16, swizzled) ----
#pragma unroll
    for (int j = 0; j < 6; ++j) {
        const int coln = ct[j] * 16 + c16;          // 0..383
        const float bv = qkv_b[coln];
        const int d = (j & 1) * 16 + c16;           // head-local dim 0..31
#pragma unroll
        for (int mt = 0; mt < 4; ++mt) {
#pragma unroll
            for (int r = 0; r < 4; ++r) {
                const int row = mt * 16 + q4 * 4 + r;
                float v = acc[mt][j][r] + bv;
                if (j < 2) {            // Q (scaled)
                    v *= QKV_SCALE;
                    const int off = WB + (((row << 7) + (d << 1)) ^ ((row & 7) << 4));
                    *(bf16_t*)&smem[off] = (bf16_t)v;
                } else if (j < 4) {     // K
                    const int off = WB + (((row << 7) + ((32 + d) << 1)) ^ ((row & 7) << 4));
                    *(bf16_t*)&smem[off] = (bf16_t)v;
                } else {                // V transposed: vt[dim][key]
                    const int off = VB + (((d << 7) + (row << 1)) ^ ((d & 7) << 4));
                    *(bf16_t*)&smem[off] = (bf16_t)v;
                }
            }
        }
    }

    // ---- S = Q @ K^T (per wave = per head), contraction K=32 -> 1 step ----
    f32x4 sacc[4][4];
#pragma unroll
    for (int mt = 0; mt < 4; ++mt)
#pragma unroll
        for (int nt = 0; nt < 4; ++nt) sacc[mt][nt] = zf;

    {
        bf16x8 afr[4];
#pragma unroll
        for (int mt = 0; mt < 4; ++mt) {
            const int qrow = mt * 16 + c16;
            const int off = WB + (((qrow << 7) + ((q4 * 8) << 1)) ^ ((qrow & 7) << 4));
            afr[mt] = *(const bf16x8*)&smem[off];
        }
#pragma unroll
        for (int nt = 0; nt < 4; ++nt) {
            const int krow = nt * 16 + c16;
            const int off = WB + (((krow << 7) + ((32 + q4 * 8) << 1)) ^ ((krow & 7) << 4));
            const bf16x8 bfr = *(const bf16x8*)&smem[off];
#pragma unroll
            for (int mt = 0; mt < 4; ++mt)
                sacc[mt][nt] = __builtin_amdgcn_mfma_f32_16x16x32_bf16(afr[mt], bfr, sacc[mt][nt], 0, 0, 0);
        }
    }

    // ---- softmax rows (bias+mask add, unnormalized P; normalize at O) ----
    const float* bmw = bm + (size_t)(((b & 63) * 4 + w)) * 2401;
    float rp[4][4];
#pragma unroll
    for (int mt = 0; mt < 4; ++mt) {
#pragma unroll
        for (int r = 0; r < 4; ++r) {
            const int row = mt * 16 + q4 * 4 + r;
            float sv[4];
            float lmax = -3.0e38f;
#pragma unroll
            for (int nt = 0; nt < 4; ++nt) {
                const int colc = nt * 16 + c16;
                const float addv = (row < 49 && colc < 49) ? bmw[row * 49 + colc] : -3.0e38f;
                const float s = sacc[mt][nt][r] + addv;
                sv[nt] = s;
                lmax = fmaxf(lmax, s);
            }
            lmax = fmaxf(lmax, __shfl_xor(lmax, 1));
            lmax = fmaxf(lmax, __shfl_xor(lmax, 2));
            lmax = fmaxf(lmax, __shfl_xor(lmax, 4));
            lmax = fmaxf(lmax, __shfl_xor(lmax, 8));
            float ssum = 0.f;
#pragma unroll
            for (int nt = 0; nt < 4; ++nt) {
                const float p = __expf(sv[nt] - lmax);
                sacc[mt][nt][r] = p;
                ssum += p;
            }
            ssum += __shfl_xor(ssum, 1);
            ssum += __shfl_xor(ssum, 2);
            ssum += __shfl_xor(ssum, 4);
            ssum += __shfl_xor(ssum, 8);
            rp[mt][r] = 1.0f / ssum;
        }
    }

    __syncthreads();   // all waves past GEMM1 xb reads; safe to reuse qk->P and xb->os

    // ---- write P (bf16) over qk region ----
#pragma unroll
    for (int mt = 0; mt < 4; ++mt)
#pragma unroll
        for (int nt = 0; nt < 4; ++nt)
#pragma unroll
            for (int r = 0; r < 4; ++r) {
                const int row  = mt * 16 + q4 * 4 + r;
                const int colc = nt * 16 + c16;
                const int off  = WB + (((row << 7) + (colc << 1)) ^ ((row & 7) << 4));
                *(bf16_t*)&smem[off] = (bf16_t)sacc[mt][nt][r];
            }

    // ---- O = P @ V  (contraction K=64 -> 2 steps), then row-normalize ----
    f32x4 oacc[4][2];
#pragma unroll
    for (int mt = 0; mt < 4; ++mt) { oacc[mt][0] = zf; oacc[mt][1] = zf; }

#pragma unroll
    for (int s = 0; s < 2; ++s) {
        bf16x8 afr[4];
#pragma unroll
        for (int mt = 0; mt < 4; ++mt) {
            const int row = mt * 16 + c16;
            const int off = WB + (((row << 7) + ((s * 32 + q4 * 8) << 1)) ^ ((row & 7) << 4));
            afr[mt] = *(const bf16x8*)&smem[off];
        }
#pragma unroll
        for (int nt = 0; nt < 2; ++nt) {
            const int dim = nt * 16 + c16;
            const int off = VB + (((dim << 7) + ((s * 32 + q4 * 8) << 1)) ^ ((dim & 7) << 4));
            const bf16x8 bfr = *(const bf16x8*)&smem[off];
#pragma unroll
            for (int mt = 0; mt < 4; ++mt)
                oacc[mt][nt] = __builtin_amdgcn_mfma_f32_16x16x32_bf16(afr[mt], bfr, oacc[mt][nt], 0, 0, 0);
        }
    }
#pragma unroll
    for (int mt = 0; mt < 4; ++mt)
#pragma unroll
        for (int nt = 0; nt < 2; ++nt)
#pragma unroll
            for (int r = 0; r < 4; ++r) oacc[mt][nt][r] *= rp[mt][r];

    // ---- O -> os (xb region), all heads ----
#pragma unroll
    for (int mt = 0; mt < 4; ++mt)
#pragma unroll
        for (int nt = 0; nt < 2; ++nt)
#pragma unroll
            for (int r = 0; r < 4; ++r) {
                const int row = mt * 16 + q4 * 4 + r;
                const int col = 32 * w + nt * 16 + c16;
                const int off = ((row << 8) + (col << 1)) ^ ((row & 7) << 4);
                *(bf16_t*)&smem[off] = (bf16_t)oacc[mt][nt][r];
            }
    __syncthreads();

    // ---- proj: Y = os @ Wp ; wave w does output cols [32w, 32w+32) ----
    f32x4 pacc[4][2];
#pragma unroll
    for (int mt = 0; mt < 4; ++mt) { pacc[mt][0] = zf; pacc[mt][1] = zf; }

#pragma unroll
    for (int ks = 0; ks < 4; ++ks) {
        bf16x8 afr[4];
#pragma unroll
        for (int mt = 0; mt < 4; ++mt) {
            const int row = mt * 16 + c16;
            const int off = ((row << 8) + ((ks * 32 + q4 * 8) << 1)) ^ ((row & 7) << 4);
            afr[mt] = *(const bf16x8*)&smem[off];
        }
#pragma unroll
        for (int nt = 0; nt < 2; ++nt) {
            const int ocol = 32 * w + nt * 16 + c16;
            const bf16x8 bfr = *(const bf16x8*)(proj_wT + ocol * 128 + ks * 32 + q4 * 8);
#pragma unroll
            for (int mt = 0; mt < 4; ++mt)
                pacc[mt][nt] = __builtin_amdgcn_mfma_f32_16x16x32_bf16(afr[mt], bfr, pacc[mt][nt], 0, 0, 0);
        }
    }

    // ---- epilogue: +proj_b, store fp32 ----
    float* og = out + (size_t)b * (49 * 128);
#pragma unroll
    for (int nt = 0; nt < 2; ++nt) {
        const int ocol = 32 * w + nt * 16 + c16;
        const float pb = proj_b[ocol];
#pragma unroll
        for (int mt = 0; mt < 4; ++mt)
#pragma unroll
            for (int r = 0; r < 4; ++r) {
                const int row = mt * 16 + q4 * 4 + r;
                if (row < 49) og[row * 128 + ocol] = pacc[mt][nt][r] + pb;
            }
    }
}

// -------------------------------------------------------------- launch ----
extern "C" void kernel_launch(void* const* d_in, const int* in_sizes, int n_in,
                              void* d_out, int out_size, void* d_ws, size_t ws_size,
                              hipStream_t stream) {
    const float* x      = (const float*)d_in[0];
    const float* mask   = (const float*)d_in[1];
    const float* qkv_w  = (const float*)d_in[2];
    const float* qkv_b  = (const float*)d_in[3];
    const float* mlp_w1 = (const float*)d_in[4];
    const float* mlp_b1 = (const float*)d_in[5];
    const float* mlp_w2 = (const float*)d_in[6];
    const float* mlp_b2 = (const float*)d_in[7];
    const float* proj_w = (const float*)d_in[8];
    const float* proj_b = (const float*)d_in[9];
    float* out = (float*)d_out;

    unsigned char* ws = (unsigned char*)d_ws;
    bf16_t* qkv_wT  = (bf16_t*)(ws + WS_QKVWT);
    bf16_t* proj_wT = (bf16_t*)(ws + WS_PROJWT);
    float*  bm      = (float*)(ws + WS_BM);

    hipLaunchKernelGGL(prep_kernel, dim3(266), dim3(256), 0, stream,
                       mask, qkv_w, mlp_w1, mlp_b1, mlp_w2, mlp_b2, proj_w,
                       qkv_wT, proj_wT, bm);
    hipLaunchKernelGGL(swin_main_kernel, dim3(16384), dim3(256), 0, stream,
                       x, qkv_b, proj_b, qkv_wT, proj_wT, bm, out);
}